// Round 1
// baseline (1022.280 us; speedup 1.0000x reference)
//
#include <hip/hip_runtime.h>
#include <hip/hip_bf16.h>

// Problem constants (match reference; runtime values read from in_sizes too)
#define D_DIM 256
#define H_HEADS 8
#define DH_DIM 32
#define EPS_LN 1e-5f
#define NEG_SLOPE 0.2f

typedef __bf16 bf16x8 __attribute__((ext_vector_type(8)));
typedef unsigned short ushortx8 __attribute__((ext_vector_type(8)));
typedef float floatx4 __attribute__((ext_vector_type(4)));

__device__ inline unsigned short f2bf(float f) {
    __hip_bfloat16 h = __float2bfloat16(f);
    return __builtin_bit_cast(unsigned short, h);
}
__device__ inline float bf2f(unsigned short u) {
    unsigned int x = ((unsigned int)u) << 16;
    return __builtin_bit_cast(float, x);
}

// ---------------------------------------------------------------------------
// Transpose + bf16-convert a 256x256 weight matrix: Wt[n][k] = bf16(W[k][n])
// ---------------------------------------------------------------------------
__global__ void wtrans_kernel(const float* __restrict__ W, unsigned short* __restrict__ Wt) {
    int idx = blockIdx.x * 256 + threadIdx.x;   // 65536 threads
    int n = idx >> 8, k = idx & 255;
    Wt[n * 256 + k] = f2bf(W[k * 256 + n]);
}

// ---------------------------------------------------------------------------
// LayerNorm + ReLU, one wave (64 lanes) per row of 256
// ---------------------------------------------------------------------------
__global__ __launch_bounds__(256) void ln_relu_kernel(
        const float* __restrict__ x, const float* __restrict__ g,
        const float* __restrict__ b, float* __restrict__ y, int nrows) {
    int row = blockIdx.x * 4 + (threadIdx.x >> 6);
    if (row >= nrows) return;
    int lane = threadIdx.x & 63;
    const float* xp = x + (size_t)row * D_DIM;
    float v[4], s = 0.f, s2 = 0.f;
#pragma unroll
    for (int j = 0; j < 4; ++j) {
        v[j] = xp[lane + 64 * j];
        s += v[j]; s2 += v[j] * v[j];
    }
#pragma unroll
    for (int m = 32; m >= 1; m >>= 1) {
        s += __shfl_xor(s, m, 64);
        s2 += __shfl_xor(s2, m, 64);
    }
    float mean = s * (1.f / D_DIM);
    float var = s2 * (1.f / D_DIM) - mean * mean;
    float rstd = rsqrtf(var + EPS_LN);
    float* yp = y + (size_t)row * D_DIM;
#pragma unroll
    for (int j = 0; j < 4; ++j) {
        int d = lane + 64 * j;
        float t = (v[j] - mean) * rstd * g[d] + b[d];
        yp[d] = fmaxf(t, 0.f);
    }
}

// ---------------------------------------------------------------------------
// bf16-MFMA GEMM: out[M,256] = A[M,256] @ W[256,256] + bias (+ residual)
// A fp32, W pre-transposed bf16 (Wt[n][k]).  Block tile 128x128, 4 waves,
// each wave 64x64 via 4x4 grid of 16x16x32 MFMAs.  LDS stride 40 (pad 8).
// ---------------------------------------------------------------------------
template <int OUT_BF16, int HAS_RES>
__global__ __launch_bounds__(256) void gemm256_kernel(
        const float* __restrict__ A, const unsigned short* __restrict__ Wt,
        const float* __restrict__ bias, const float* __restrict__ res,
        void* __restrict__ out, int M) {
    __shared__ unsigned short As[128 * 40];
    __shared__ unsigned short Bs[128 * 40];
    const int n0 = blockIdx.x * 128;
    const int m0 = blockIdx.y * 128;
    const int t = threadIdx.x;
    const int lane = t & 63;
    const int wave = t >> 6;
    const int q = lane >> 4;       // quad 0..3
    const int l16 = lane & 15;
    const int wm = (wave & 1) * 64;
    const int wn = (wave >> 1) * 64;
    const int sm = t >> 1;         // staging row 0..127
    const int sh = t & 1;          // staging half (16 elems each)

    floatx4 acc[4][4] = {};

    for (int kt = 0; kt < 8; ++kt) {
        const int k0 = kt * 32;
        // ---- stage A (fp32 -> bf16) ----
        {
            int r = m0 + sm;
            unsigned short tmp[16];
            if (r < M) {
                const float4* ap = (const float4*)(A + (size_t)r * 256 + k0 + sh * 16);
#pragma unroll
                for (int i = 0; i < 4; ++i) {
                    float4 v = ap[i];
                    tmp[i * 4 + 0] = f2bf(v.x);
                    tmp[i * 4 + 1] = f2bf(v.y);
                    tmp[i * 4 + 2] = f2bf(v.z);
                    tmp[i * 4 + 3] = f2bf(v.w);
                }
            } else {
#pragma unroll
                for (int i = 0; i < 16; ++i) tmp[i] = 0;
            }
            *(ushortx8*)&As[sm * 40 + sh * 16] = *(ushortx8*)&tmp[0];
            *(ushortx8*)&As[sm * 40 + sh * 16 + 8] = *(ushortx8*)&tmp[8];
        }
        // ---- stage B (already bf16, transposed: Bs[n][k]) ----
        {
            const unsigned short* wp = Wt + (size_t)(n0 + sm) * 256 + k0 + sh * 16;
            ushortx8 b0 = *(const ushortx8*)wp;
            ushortx8 b1 = *(const ushortx8*)(wp + 8);
            *(ushortx8*)&Bs[sm * 40 + sh * 16] = b0;
            *(ushortx8*)&Bs[sm * 40 + sh * 16 + 8] = b1;
        }
        __syncthreads();
        bf16x8 af[4], bfr[4];
#pragma unroll
        for (int mi = 0; mi < 4; ++mi)
            af[mi] = __builtin_bit_cast(bf16x8,
                *(const ushortx8*)&As[(wm + mi * 16 + l16) * 40 + q * 8]);
#pragma unroll
        for (int ni = 0; ni < 4; ++ni)
            bfr[ni] = __builtin_bit_cast(bf16x8,
                *(const ushortx8*)&Bs[(wn + ni * 16 + l16) * 40 + q * 8]);
#pragma unroll
        for (int mi = 0; mi < 4; ++mi)
#pragma unroll
            for (int ni = 0; ni < 4; ++ni)
                acc[mi][ni] = __builtin_amdgcn_mfma_f32_16x16x32_bf16(
                    af[mi], bfr[ni], acc[mi][ni], 0, 0, 0);
        __syncthreads();
    }
    // ---- epilogue: D[row=q*4+r][col=l16] per 16x16 tile ----
#pragma unroll
    for (int mi = 0; mi < 4; ++mi) {
#pragma unroll
        for (int ni = 0; ni < 4; ++ni) {
            int col = n0 + wn + ni * 16 + l16;
            float bcol = bias[col];
#pragma unroll
            for (int r = 0; r < 4; ++r) {
                int row = m0 + wm + mi * 16 + q * 4 + r;
                if (row < M) {
                    float v = acc[mi][ni][r] + bcol;
                    if (HAS_RES) v += res[(size_t)row * 256 + col];
                    if (OUT_BF16)
                        ((unsigned short*)out)[(size_t)row * 256 + col] = f2bf(v);
                    else
                        ((float*)out)[(size_t)row * 256 + col] = v;
                }
            }
        }
    }
}

// ---------------------------------------------------------------------------
// CSR build: histogram, single-block scan, scatter
// ---------------------------------------------------------------------------
__global__ void hist_kernel(const int* __restrict__ tgt, int* __restrict__ counts, int E) {
    int i = blockIdx.x * 256 + threadIdx.x;
    if (i < E) atomicAdd(&counts[tgt[i]], 1);
}

__global__ __launch_bounds__(1024) void scan_kernel(
        const int* __restrict__ counts, int* __restrict__ offs, int n) {
    __shared__ int lds[1024];
    int t = threadIdx.x;
    int CH = (n + 1023) >> 10;
    int beg = t * CH, end = min(beg + CH, n);
    int s = 0;
    for (int i = beg; i < end; ++i) s += counts[i];
    lds[t] = s;
    __syncthreads();
    for (int off = 1; off < 1024; off <<= 1) {
        int v = (t >= off) ? lds[t - off] : 0;
        __syncthreads();
        lds[t] += v;
        __syncthreads();
    }
    int run = lds[t] - s;   // exclusive prefix
    for (int i = beg; i < end; ++i) { offs[i] = run; run += counts[i]; }
    if (t == 1023) offs[n] = lds[1023];
}

__global__ void scatter_kernel(const int* __restrict__ tgt, const int* __restrict__ offs,
                               int* __restrict__ cursor, int* __restrict__ elist, int E) {
    int i = blockIdx.x * 256 + threadIdx.x;
    if (i < E) {
        int tg = tgt[i];
        int p = atomicAdd(&cursor[tg], 1);
        elist[offs[tg] + p] = i;
    }
}

// ---------------------------------------------------------------------------
// Per-target fused: edge softmax + aggregation + gat_bias + residual + LN2 + relu
// One wave per target.  Lane l owns features d = l + 64*j, j=0..3.
// Head of feature d is d>>5; shfl_xor masks {1..16} reduce within 32-lane halves,
// which is exactly a per-head reduction for each j.
// ---------------------------------------------------------------------------
__global__ __launch_bounds__(256) void aggregate_kernel(
        const unsigned short* __restrict__ xl, const float* __restrict__ xr,
        const float* __restrict__ prev, const int* __restrict__ esrc,
        const int* __restrict__ elist, const int* __restrict__ offs,
        const float* __restrict__ att, const float* __restrict__ gbias,
        const float* __restrict__ g2, const float* __restrict__ b2,
        float* __restrict__ x_skip, float* __restrict__ h2, int nsp) {
    int tgt = blockIdx.x * 4 + (threadIdx.x >> 6);
    if (tgt >= nsp) return;
    int lane = threadIdx.x & 63;
    float xrv[4], attv[4], acc[4] = {0.f, 0.f, 0.f, 0.f}, den[4] = {0.f, 0.f, 0.f, 0.f};
#pragma unroll
    for (int j = 0; j < 4; ++j) {
        int d = lane + 64 * j;
        xrv[j] = xr[(size_t)tgt * D_DIM + d];
        attv[j] = att[d];
    }
    int beg = offs[tgt], end = offs[tgt + 1];
    for (int i = beg; i < end; ++i) {
        int e = elist[i];
        int src = esrc[e];
        const unsigned short* xp = xl + (size_t)src * D_DIM;
        float xlv[4], p[4];
#pragma unroll
        for (int j = 0; j < 4; ++j) {
            xlv[j] = bf2f(xp[lane + 64 * j]);
            float tsum = xlv[j] + xrv[j];
            float lr = tsum > 0.f ? tsum : NEG_SLOPE * tsum;
            p[j] = lr * attv[j];
        }
#pragma unroll
        for (int m = 16; m >= 1; m >>= 1) {
#pragma unroll
            for (int j = 0; j < 4; ++j) p[j] += __shfl_xor(p[j], m, 64);
        }
#pragma unroll
        for (int j = 0; j < 4; ++j) {
            float ex = __expf(p[j]);   // |e| small: max-subtraction unnecessary
            den[j] += ex;
            acc[j] += ex * xlv[j];
        }
    }
    float x[4], s = 0.f, s2 = 0.f;
#pragma unroll
    for (int j = 0; j < 4; ++j) {
        int d = lane + 64 * j;
        float o = acc[j] / (den[j] + 1e-16f);
        float v = prev[(size_t)tgt * D_DIM + d] + o + gbias[d];
        x[j] = v; s += v; s2 += v * v;
    }
#pragma unroll
    for (int m = 32; m >= 1; m >>= 1) {
        s += __shfl_xor(s, m, 64);
        s2 += __shfl_xor(s2, m, 64);
    }
    float mean = s * (1.f / D_DIM);
    float var = s2 * (1.f / D_DIM) - mean * mean;
    float rstd = rsqrtf(var + EPS_LN);
#pragma unroll
    for (int j = 0; j < 4; ++j) {
        int d = lane + 64 * j;
        x_skip[(size_t)tgt * D_DIM + d] = x[j];
        float t2 = (x[j] - mean) * rstd * g2[d] + b2[d];
        h2[(size_t)tgt * D_DIM + d] = fmaxf(t2, 0.f);
    }
}

// ---------------------------------------------------------------------------
extern "C" void kernel_launch(void* const* d_in, const int* in_sizes, int n_in,
                              void* d_out, int out_size, void* d_ws, size_t ws_size,
                              hipStream_t stream) {
    const float* proj = (const float*)d_in[0];
    const float* prev = (const float*)d_in[1];
    const float* Wl   = (const float*)d_in[2];
    const float* bl   = (const float*)d_in[3];
    const float* Wr   = (const float*)d_in[4];
    const float* br   = (const float*)d_in[5];
    const float* att  = (const float*)d_in[6];
    const float* gbias= (const float*)d_in[7];
    const float* ln1g = (const float*)d_in[8];
    const float* ln1b = (const float*)d_in[9];
    const float* ln2g = (const float*)d_in[10];
    const float* ln2b = (const float*)d_in[11];
    const float* Wm   = (const float*)d_in[12];
    const float* mb   = (const float*)d_in[13];
    const int* esrc   = (const int*)d_in[14];
    const int* etgt   = (const int*)d_in[15];

    const int NP = in_sizes[0] / D_DIM;   // 400000
    const int NS = in_sizes[1] / D_DIM;   // 40000
    const int E  = in_sizes[14];          // 400000

    // workspace carve-up
    char* base = (char*)d_ws;
    size_t off = 0;
    auto carve = [&](size_t bytes) {
        char* p = base + off;
        off += (bytes + 255) & ~(size_t)255;
        return p;
    };
    unsigned short* xl    = (unsigned short*)carve((size_t)NP * D_DIM * 2);
    float* x_agg          = (float*)carve((size_t)NS * D_DIM * 4);
    float* xr             = (float*)carve((size_t)NS * D_DIM * 4);
    float* x_skip         = (float*)carve((size_t)NS * D_DIM * 4);
    float* h2             = (float*)carve((size_t)NS * D_DIM * 4);
    unsigned short* Wt_l  = (unsigned short*)carve((size_t)D_DIM * D_DIM * 2);
    unsigned short* Wt_r  = (unsigned short*)carve((size_t)D_DIM * D_DIM * 2);
    unsigned short* Wt_m  = (unsigned short*)carve((size_t)D_DIM * D_DIM * 2);
    int* counts           = (int*)carve((size_t)NS * 4 * 2);   // counts + cursor contiguous
    int* cursor           = counts + NS;
    int* offs             = (int*)carve((size_t)(NS + 1) * 4);
    int* elist            = (int*)carve((size_t)E * 4);

    // zero counts + cursor (ws is poisoned each call)
    hipMemsetAsync(counts, 0, (size_t)NS * 4 * 2, stream);

    // weight transpose + bf16 convert
    wtrans_kernel<<<256, 256, 0, stream>>>(Wl, Wt_l);
    wtrans_kernel<<<256, 256, 0, stream>>>(Wr, Wt_r);
    wtrans_kernel<<<256, 256, 0, stream>>>(Wm, Wt_m);

    // x_agg = relu(LN1(prev))
    ln_relu_kernel<<<(NS + 3) / 4, 256, 0, stream>>>(prev, ln1g, ln1b, x_agg, NS);

    // xr = x_agg @ Wr + br   (fp32 out)
    gemm256_kernel<0, 0><<<dim3(2, (NS + 127) / 128), 256, 0, stream>>>(
        x_agg, Wt_r, br, nullptr, (void*)xr, NS);

    // xl = proj @ Wl + bl    (bf16 out)
    gemm256_kernel<1, 0><<<dim3(2, (NP + 127) / 128), 256, 0, stream>>>(
        proj, Wt_l, bl, nullptr, (void*)xl, NP);

    // CSR build
    hist_kernel<<<(E + 255) / 256, 256, 0, stream>>>(etgt, counts, E);
    scan_kernel<<<1, 1024, 0, stream>>>(counts, offs, NS);
    scatter_kernel<<<(E + 255) / 256, 256, 0, stream>>>(etgt, offs, cursor, elist, E);

    // fused edge softmax + aggregation + residual + LN2 + relu
    aggregate_kernel<<<(NS + 3) / 4, 256, 0, stream>>>(
        xl, xr, prev, esrc, elist, offs, att, gbias, ln2g, ln2b, x_skip, h2, NS);

    // out = x_skip + h2 @ mlp_W + mlp_b
    gemm256_kernel<0, 1><<<dim3(2, (NS + 127) / 128), 256, 0, stream>>>(
        h2, Wt_m, mb, x_skip, d_out, NS);
}